// Round 1
// baseline (518.243 us; speedup 1.0000x reference)
//
#include <hip/hip_runtime.h>
#include <hip/hip_fp16.h>
#include <math.h>

#define HDIM 1024
#define NEXP 8
#define FDIM 4096
#define CAP 512
#define LDP 40   // LDS pitch in halves: multiple of 8 (16B-aligned b128), bank spread 2-way max

typedef _Float16 half8 __attribute__((ext_vector_type(8)));
typedef float floatx4 __attribute__((ext_vector_type(4)));

// ---------------- gating: one wave per token t in 0..511 ----------------
__global__ __launch_bounds__(64)
void moe_gate_kernel(const float* __restrict__ x, const float* __restrict__ Wg,
                     const float* __restrict__ bg,
                     float* __restrict__ wgt, int* __restrict__ src, int* __restrict__ ord) {
    const int t = blockIdx.x;
    const int lane = threadIdx.x;
    const float* xr = x + (size_t)t * HDIM;
    float acc[NEXP];
#pragma unroll
    for (int e = 0; e < NEXP; e++) acc[e] = 0.f;
    for (int i = lane; i < HDIM; i += 64) {
        float xv = xr[i];
        const float* wr = Wg + (size_t)i * NEXP;
#pragma unroll
        for (int e = 0; e < NEXP; e++) acc[e] += xv * wr[e];
    }
#pragma unroll
    for (int e = 0; e < NEXP; e++) {
        float v = acc[e];
#pragma unroll
        for (int off = 1; off < 64; off <<= 1) v += __shfl_xor(v, off, 64);
        acc[e] = v;
    }
    if (lane == 0) {
        float p[NEXP];
        float mx = -1e30f;
#pragma unroll
        for (int e = 0; e < NEXP; e++) { acc[e] += bg[e]; mx = fmaxf(mx, acc[e]); }
        float s = 0.f;
#pragma unroll
        for (int e = 0; e < NEXP; e++) { p[e] = expf(acc[e] - mx); s += p[e]; }
        float inv = 1.f / s;
        float s2 = 0.f;
#pragma unroll
        for (int e = 0; e < NEXP; e++) { p[e] *= inv; s2 += p[e]; }
        float norm = 1.f / (s2 + 1e-9f);
        int used = 0;
        // selection sort descending; strict > scanning ascending index == jax top_k tie rule
        for (int r = 0; r < 8; r++) {
            int best = 0; float bv = -1.f;
            for (int e = 0; e < NEXP; e++) {
                if (!((used >> e) & 1) && p[e] > bv) { bv = p[e]; best = e; }
            }
            used |= 1 << best;
            wgt[best * CAP + t] = p[best] * norm;
            src[best * CAP + t] = 4 * t + (r >> 1);   // faithful tok = f//K bug
            ord[t * 8 + r] = best;
        }
    }
}

// ---------------- dispatch: buf[e][t][:] = w * x[src] (fp16) ----------------
__global__ __launch_bounds__(256)
void moe_dispatch_kernel(const float* __restrict__ x, const float* __restrict__ wgt,
                         const int* __restrict__ src, __half* __restrict__ buf) {
    const int row = blockIdx.x;           // e*CAP + t
    const int tid = threadIdx.x;
    const float w = wgt[row];
    const int s = src[row];
    float4 v = ((const float4*)(x + (size_t)s * HDIM))[tid];
    __half2 h0 = __floats2half2_rn(v.x * w, v.y * w);
    __half2 h1 = __floats2half2_rn(v.z * w, v.w * w);
    __half2* o = (__half2*)(buf + (size_t)row * HDIM);
    o[tid * 2]     = h0;
    o[tid * 2 + 1] = h1;
}

// ---------------- grouped GEMM: C[e] = act(A[e] @ B[e] + bias[e]) ----------------
// A: [E][512][Kdim] fp16 row-major.  B: [E][Kdim][Ndim] fp32 row-major (converted in staging).
// GELU=true: C fp16 (hmid), exact gelu. GELU=false: C fp32 (out_buf).
template <int Kdim, int Ndim, bool GELU>
__global__ __launch_bounds__(256)
void moe_gemm_kernel(const __half* __restrict__ A, const float* __restrict__ Bw,
                     const float* __restrict__ bias, void* __restrict__ Cout) {
    __shared__ __align__(16) __half As[128 * LDP];
    __shared__ __align__(16) __half Bs[128 * LDP];

    const int tid = threadIdx.x;
    const int lane = tid & 63;
    const int wave = tid >> 6;
    const int wm = wave >> 1, wn = wave & 1;
    const int quad = lane >> 4, l15 = lane & 15;

    const int e = blockIdx.z;
    const int mBase = blockIdx.y * 128;
    const int nBase = blockIdx.x * 128;

    const __half* Ae = A + ((size_t)e * 512 + mBase) * Kdim;
    const float* Be = Bw + (size_t)e * Kdim * Ndim + nBase;

    // staging maps
    const int arow = tid >> 1;            // 0..127
    const int acol = (tid & 1) * 16;      // 0 / 16
    const int brow = tid >> 3;            // 0..31 (k)
    const int bcol0 = (tid & 7) * 4;      // 0..28

    floatx4 acc[4][4] = {};

    for (int k0 = 0; k0 < Kdim; k0 += 32) {
        const __half* Ag = Ae + (size_t)arow * Kdim + k0 + acol;
        int4 av0 = *(const int4*)Ag;
        int4 av1 = *(const int4*)(Ag + 8);
        const float* Br = Be + (size_t)(k0 + brow) * Ndim + bcol0;
        float4 bv0 = *(const float4*)(Br);
        float4 bv1 = *(const float4*)(Br + 32);
        float4 bv2 = *(const float4*)(Br + 64);
        float4 bv3 = *(const float4*)(Br + 96);

        __syncthreads();   // previous iteration's LDS reads complete

        *(int4*)&As[arow * LDP + acol]     = av0;
        *(int4*)&As[arow * LDP + acol + 8] = av1;
        {
            float4 bb[4] = {bv0, bv1, bv2, bv3};
#pragma unroll
            for (int i = 0; i < 4; i++) {
                const int n = bcol0 + 32 * i;
                Bs[(n + 0) * LDP + brow] = __float2half(bb[i].x);
                Bs[(n + 1) * LDP + brow] = __float2half(bb[i].y);
                Bs[(n + 2) * LDP + brow] = __float2half(bb[i].z);
                Bs[(n + 3) * LDP + brow] = __float2half(bb[i].w);
            }
        }
        __syncthreads();

        half8 af[4], bf[4];
#pragma unroll
        for (int i = 0; i < 4; i++) {
            af[i] = *(const half8*)&As[(wm * 64 + i * 16 + l15) * LDP + quad * 8];
            bf[i] = *(const half8*)&Bs[(wn * 64 + i * 16 + l15) * LDP + quad * 8];
        }
#pragma unroll
        for (int mi = 0; mi < 4; mi++)
#pragma unroll
            for (int ni = 0; ni < 4; ni++)
                acc[mi][ni] = __builtin_amdgcn_mfma_f32_16x16x32_f16(af[mi], bf[ni], acc[mi][ni], 0, 0, 0);
    }

    // epilogue: C[row][col], row=(lane>>4)*4+r, col=lane&15 (verified m89 mapping)
    const float* be = bias + (size_t)e * Ndim + nBase;
    if (GELU) {
        __half* C = (__half*)Cout + ((size_t)e * 512 + mBase) * Ndim + nBase;
#pragma unroll
        for (int mi = 0; mi < 4; mi++) {
#pragma unroll
            for (int ni = 0; ni < 4; ni++) {
                const int col = wn * 64 + ni * 16 + l15;
                const float b = be[col];
#pragma unroll
                for (int r = 0; r < 4; r++) {
                    const int row = wm * 64 + mi * 16 + quad * 4 + r;
                    float v = acc[mi][ni][r] + b;
                    v = 0.5f * v * (1.f + erff(v * 0.70710678118f));
                    C[(size_t)row * Ndim + col] = __float2half(v);
                }
            }
        }
    } else {
        float* C = (float*)Cout + ((size_t)e * 512 + mBase) * Ndim + nBase;
#pragma unroll
        for (int mi = 0; mi < 4; mi++) {
#pragma unroll
            for (int ni = 0; ni < 4; ni++) {
                const int col = wn * 64 + ni * 16 + l15;
                const float b = be[col];
#pragma unroll
                for (int r = 0; r < 4; r++) {
                    const int row = wm * 64 + mi * 16 + quad * 4 + r;
                    C[(size_t)row * Ndim + col] = acc[mi][ni][r] + b;
                }
            }
        }
    }
}

// ---------------- combine: y[4t+q] = outb[ord[t][2q],t] + outb[ord[t][2q+1],t] ----------------
__global__ __launch_bounds__(256)
void moe_combine_kernel(const float* __restrict__ outb, const int* __restrict__ ord,
                        float* __restrict__ y) {
    const int j = blockIdx.x;          // 0..2047
    const int t = j >> 2, q = j & 3;
    const int e1 = ord[t * 8 + 2 * q];
    const int e2 = ord[t * 8 + 2 * q + 1];
    float4 a = ((const float4*)(outb + ((size_t)e1 * CAP + t) * HDIM))[threadIdx.x];
    float4 b = ((const float4*)(outb + ((size_t)e2 * CAP + t) * HDIM))[threadIdx.x];
    float4 o = {a.x + b.x, a.y + b.y, a.z + b.z, a.w + b.w};
    ((float4*)(y + (size_t)j * HDIM))[threadIdx.x] = o;
}

extern "C" void kernel_launch(void* const* d_in, const int* in_sizes, int n_in,
                              void* d_out, int out_size, void* d_ws, size_t ws_size,
                              hipStream_t stream) {
    const float* x  = (const float*)d_in[0];
    const float* Wg = (const float*)d_in[1];
    const float* bg = (const float*)d_in[2];
    const float* W1 = (const float*)d_in[3];
    const float* b1 = (const float*)d_in[4];
    const float* W2 = (const float*)d_in[5];
    const float* b2 = (const float*)d_in[6];
    float* out = (float*)d_out;

    char* ws = (char*)d_ws;
    __half* buf  = (__half*)(ws);                       // 8 MB : [E][512][H] fp16
    __half* hmid = (__half*)(ws + (size_t)(8  << 20));  // 32 MB: [E][512][F] fp16
    float*  outb = (float*) (ws + (size_t)(40 << 20));  // 16 MB: [E][512][H] fp32
    float*  wgt  = (float*) (ws + (size_t)(56 << 20));           // E*CAP
    int*    src  = (int*)   (ws + (size_t)(56 << 20) + 16384);   // E*CAP
    int*    ord  = (int*)   (ws + (size_t)(56 << 20) + 32768);   // CAP*8

    // y rows >= 2048 are exactly zero; aux loss is exactly 0 (em all-ones -> KL=0)
    hipMemsetAsync(d_out, 0, (size_t)out_size * sizeof(float), stream);

    moe_gate_kernel<<<CAP, 64, 0, stream>>>(x, Wg, bg, wgt, src, ord);
    moe_dispatch_kernel<<<NEXP * CAP, 256, 0, stream>>>(x, wgt, src, buf);
    moe_gemm_kernel<HDIM, FDIM, true><<<dim3(FDIM / 128, 4, NEXP), 256, 0, stream>>>(buf, W1, b1, hmid);
    moe_gemm_kernel<FDIM, HDIM, false><<<dim3(HDIM / 128, 4, NEXP), 256, 0, stream>>>(hmid, W2, b2, outb);
    moe_combine_kernel<<<2048, 256, 0, stream>>>(outb, ord, out);
}

// Round 2
// 473.201 us; speedup vs baseline: 1.0952x; 1.0952x over previous
//
#include <hip/hip_runtime.h>
#include <hip/hip_fp16.h>
#include <math.h>

#define HDIM 1024
#define NEXP 8
#define FDIM 4096
#define CAP 512

typedef _Float16 half8 __attribute__((ext_vector_type(8)));
typedef float floatx4 __attribute__((ext_vector_type(4)));

// async global->LDS, 16B per lane; lds base must be wave-uniform (HW: dest = base + lane*16)
__device__ __forceinline__ void glds16(const __half* g, __half* ldsbase) {
    __builtin_amdgcn_global_load_lds(
        (const __attribute__((address_space(1))) void*)g,
        (__attribute__((address_space(3))) void*)ldsbase,
        16, 0, 0);
}

// ---------------- gating: one wave per token t in 0..511 ----------------
__global__ __launch_bounds__(64)
void moe_gate_kernel(const float* __restrict__ x, const float* __restrict__ Wg,
                     const float* __restrict__ bg,
                     float* __restrict__ wgt, int* __restrict__ src, int* __restrict__ ord) {
    const int t = blockIdx.x;
    const int lane = threadIdx.x;
    const float* xr = x + (size_t)t * HDIM;
    float acc[NEXP];
#pragma unroll
    for (int e = 0; e < NEXP; e++) acc[e] = 0.f;
    for (int i = lane; i < HDIM; i += 64) {
        float xv = xr[i];
        const float* wr = Wg + (size_t)i * NEXP;
#pragma unroll
        for (int e = 0; e < NEXP; e++) acc[e] += xv * wr[e];
    }
#pragma unroll
    for (int e = 0; e < NEXP; e++) {
        float v = acc[e];
#pragma unroll
        for (int off = 1; off < 64; off <<= 1) v += __shfl_xor(v, off, 64);
        acc[e] = v;
    }
    if (lane == 0) {
        float p[NEXP];
        float mx = -1e30f;
#pragma unroll
        for (int e = 0; e < NEXP; e++) { acc[e] += bg[e]; mx = fmaxf(mx, acc[e]); }
        float s = 0.f;
#pragma unroll
        for (int e = 0; e < NEXP; e++) { p[e] = expf(acc[e] - mx); s += p[e]; }
        float inv = 1.f / s;
        float s2 = 0.f;
#pragma unroll
        for (int e = 0; e < NEXP; e++) { p[e] *= inv; s2 += p[e]; }
        float norm = 1.f / (s2 + 1e-9f);
        int used = 0;
        // selection sort descending; strict > scanning ascending index == jax top_k tie rule
        for (int r = 0; r < 8; r++) {
            int best = 0; float bv = -1.f;
            for (int e = 0; e < NEXP; e++) {
                if (!((used >> e) & 1) && p[e] > bv) { bv = p[e]; best = e; }
            }
            used |= 1 << best;
            wgt[best * CAP + t] = p[best] * norm;
            src[best * CAP + t] = 4 * t + (r >> 1);   // faithful tok = f//K bug
            ord[t * 8 + r] = best;
        }
    }
}

// ---------------- dispatch: buf[e][t][:] = w * x[src] (fp16) ----------------
__global__ __launch_bounds__(256)
void moe_dispatch_kernel(const float* __restrict__ x, const float* __restrict__ wgt,
                         const int* __restrict__ src, __half* __restrict__ buf) {
    const int row = blockIdx.x;           // e*CAP + t
    const int tid = threadIdx.x;
    const float w = wgt[row];
    const int s = src[row];
    float4 v = ((const float4*)(x + (size_t)s * HDIM))[tid];
    __half2 h0 = __floats2half2_rn(v.x * w, v.y * w);
    __half2 h1 = __floats2half2_rn(v.z * w, v.w * w);
    __half2* o = (__half2*)(buf + (size_t)row * HDIM);
    o[tid * 2]     = h0;
    o[tid * 2 + 1] = h1;
}

// ---------------- transpose+convert: W[e][R][C] fp32 -> WT[e][C][R] fp16 ----------------
__global__ __launch_bounds__(256)
void transpose_convert_kernel(const float* __restrict__ W, __half* __restrict__ WT,
                              int R, int C) {
    __shared__ float tile[64][65];   // +1 pad: column reads conflict-free
    const int e = blockIdx.z;
    const int tr = blockIdx.y * 64;
    const int tc = blockIdx.x * 64;
    const float* We = W + (size_t)e * R * C;
    __half* WTe = WT + (size_t)e * R * C;
    const int tid = threadIdx.x;
    {
        const int c0 = (tid & 15) * 4;
        const int r0 = tid >> 4;     // 0..15
#pragma unroll
        for (int it = 0; it < 4; it++) {
            const int r = r0 + it * 16;
            float4 v = *(const float4*)(We + (size_t)(tr + r) * C + tc + c0);
            tile[r][c0] = v.x; tile[r][c0 + 1] = v.y; tile[r][c0 + 2] = v.z; tile[r][c0 + 3] = v.w;
        }
    }
    __syncthreads();
    {
        const int cc = tid >> 2;            // 0..63 (column of W = row of WT)
        const int rr0 = (tid & 3) * 16;     // 16 contiguous output elements
        __half h[16];
#pragma unroll
        for (int i = 0; i < 16; i++) h[i] = __float2half(tile[rr0 + i][cc]);
        __half* dst = WTe + (size_t)(tc + cc) * R + tr + rr0;
        *(int4*)dst = *(int4*)h;
        *(int4*)(dst + 8) = *(int4*)(h + 8);
    }
}

// ---------------- m97-style grouped GEMM: C[e] = act(A[e] @ BT[e]^T + bias[e]) ----------------
// A : [E][512][Kd] fp16 k-contig.  BT: [E][Nd][Kd] fp16 k-contig (pre-transposed weights).
// 128x128 block tile, 4 waves 2x2, 4x4 16x16x32 frags/wave, glds width-16 staging.
template <int Kd, int Nd, bool GELU, int KSPLIT>
__global__ __launch_bounds__(256, 4)
void moe_gemm_kernel(const __half* __restrict__ A, const __half* __restrict__ BT,
                     const float* __restrict__ bias, void* __restrict__ Cout) {
    __shared__ __align__(16) __half As[128 * 32];
    __shared__ __align__(16) __half Bs[128 * 32];

    const int tid = threadIdx.x;
    const int lane = tid & 63;
    const int wu = __builtin_amdgcn_readfirstlane(tid >> 6);
    const int wm = wu >> 1, wn = wu & 1;
    const int quad = lane >> 4, l15 = lane & 15;

    const int e  = blockIdx.z / KSPLIT;
    const int ks = blockIdx.z % KSPLIT;
    const int mBase = blockIdx.y * 128;
    const int nBase = blockIdx.x * 128;
    const int kLen = Kd / KSPLIT;

    const __half* Ae = A + ((size_t)e * 512 + mBase) * Kd + (size_t)ks * kLen;
    const __half* Be = BT + ((size_t)e * Nd + nBase) * Kd + (size_t)ks * kLen;

    const int srow = lane >> 2;          // 0..15
    const int scol = (lane & 3) * 8;     // halves

    floatx4 acc[4][4] = {};

    for (int k0 = 0; k0 < kLen; k0 += 32) {
        __syncthreads();   // prior iteration's ds_reads complete before overwrite
        {
            const __half* ga = Ae + (size_t)(wu * 32 + srow) * Kd + k0 + scol;
            const __half* gb = Be + (size_t)(wu * 32 + srow) * Kd + k0 + scol;
            glds16(ga,                    As + (wu * 32) * 32);
            glds16(ga + (size_t)16 * Kd,  As + (wu * 32 + 16) * 32);
            glds16(gb,                    Bs + (wu * 32) * 32);
            glds16(gb + (size_t)16 * Kd,  Bs + (wu * 32 + 16) * 32);
        }
        __syncthreads();   // compiler drains vmcnt(0) here
        half8 af[4], bf[4];
#pragma unroll
        for (int i = 0; i < 4; i++) {
            af[i] = *(const half8*)&As[(wm * 64 + i * 16 + l15) * 32 + quad * 8];
            bf[i] = *(const half8*)&Bs[(wn * 64 + i * 16 + l15) * 32 + quad * 8];
        }
#pragma unroll
        for (int mi = 0; mi < 4; mi++)
#pragma unroll
            for (int ni = 0; ni < 4; ni++)
                acc[mi][ni] = __builtin_amdgcn_mfma_f32_16x16x32_f16(af[mi], bf[ni], acc[mi][ni], 0, 0, 0);
    }

    // epilogue: C[row][col], row=(lane>>4)*4+r, col=lane&15 (verified m89 mapping)
    const float* be = bias + (size_t)e * Nd + nBase;
    if (GELU) {
        __half* C = (__half*)Cout + ((size_t)e * 512 + mBase) * Nd + nBase;
#pragma unroll
        for (int mi = 0; mi < 4; mi++) {
#pragma unroll
            for (int ni = 0; ni < 4; ni++) {
                const int col = wn * 64 + ni * 16 + l15;
                const float b = be[col];
#pragma unroll
                for (int r = 0; r < 4; r++) {
                    const int row = wm * 64 + mi * 16 + quad * 4 + r;
                    float v = acc[mi][ni][r] + b;
                    v = 0.5f * v * (1.f + erff(v * 0.70710678118f));
                    C[(size_t)row * Nd + col] = __float2half(v);
                }
            }
        }
    } else {
        // K-split partials: partial ks at Cout + ks*E*512*Nd; bias only in partial 0
        float* C = (float*)Cout + (((size_t)ks * NEXP + e) * 512 + mBase) * Nd + nBase;
#pragma unroll
        for (int mi = 0; mi < 4; mi++) {
#pragma unroll
            for (int ni = 0; ni < 4; ni++) {
                const int col = wn * 64 + ni * 16 + l15;
                const float b = (ks == 0) ? be[col] : 0.f;
#pragma unroll
                for (int r = 0; r < 4; r++) {
                    const int row = wm * 64 + mi * 16 + quad * 4 + r;
                    C[(size_t)row * Nd + col] = acc[mi][ni][r] + b;
                }
            }
        }
    }
}

// ---------------- combine: y[4t+q] = sum over 2 experts x 2 K-partials; zero tail; loss=0 ----------------
__global__ __launch_bounds__(256)
void moe_combine_kernel(const float* __restrict__ outb, const int* __restrict__ ord,
                        float* __restrict__ y) {
    const int j = blockIdx.x;          // 0..8191 token row
    const int tid = threadIdx.x;
    float4* yo = (float4*)(y + (size_t)j * HDIM);
    if (j >= 2048) {
        yo[tid] = float4{0.f, 0.f, 0.f, 0.f};
        if (j == 2048 && tid == 0) y[(size_t)8192 * HDIM] = 0.f;  // aux loss: exactly 0 (em all-ones)
        return;
    }
    const int t = j >> 2, q = j & 3;
    const int e1 = ord[t * 8 + 2 * q];
    const int e2 = ord[t * 8 + 2 * q + 1];
    const size_t PSTR = (size_t)NEXP * CAP * HDIM;
    float4 a0 = ((const float4*)(outb + ((size_t)e1 * CAP + t) * HDIM))[tid];
    float4 a1 = ((const float4*)(outb + PSTR + ((size_t)e1 * CAP + t) * HDIM))[tid];
    float4 b0 = ((const float4*)(outb + ((size_t)e2 * CAP + t) * HDIM))[tid];
    float4 b1 = ((const float4*)(outb + PSTR + ((size_t)e2 * CAP + t) * HDIM))[tid];
    float4 o = {a0.x + a1.x + b0.x + b1.x, a0.y + a1.y + b0.y + b1.y,
                a0.z + a1.z + b0.z + b1.z, a0.w + a1.w + b0.w + b1.w};
    yo[tid] = o;
}

extern "C" void kernel_launch(void* const* d_in, const int* in_sizes, int n_in,
                              void* d_out, int out_size, void* d_ws, size_t ws_size,
                              hipStream_t stream) {
    const float* x  = (const float*)d_in[0];
    const float* Wg = (const float*)d_in[1];
    const float* bg = (const float*)d_in[2];
    const float* W1 = (const float*)d_in[3];
    const float* b1 = (const float*)d_in[4];
    const float* W2 = (const float*)d_in[5];
    const float* b2 = (const float*)d_in[6];
    float* out = (float*)d_out;

    char* ws = (char*)d_ws;
    __half* buf  = (__half*)(ws);                        // 8 MB : [E][512][H] fp16
    __half* hmid = (__half*)(ws + (8ull  << 20));        // 32 MB: [E][512][F] fp16
    __half* W1T  = (__half*)(ws + (40ull << 20));        // 64 MB: [E][F][H] fp16
    __half* W2T  = (__half*)(ws + (104ull << 20));       // 64 MB: [E][H][F] fp16
    float*  outb = (float*)(ws + (40ull << 20));         // 32 MB: 2 partials [E][512][H] (reuses dead W1T)
    float*  wgt  = (float*)(ws + (168ull << 20));
    int*    src  = (int*)  (ws + (168ull << 20) + 16384);
    int*    ord  = (int*)  (ws + (168ull << 20) + 32768);

    transpose_convert_kernel<<<dim3(FDIM / 64, HDIM / 64, NEXP), 256, 0, stream>>>(W1, W1T, HDIM, FDIM);
    transpose_convert_kernel<<<dim3(HDIM / 64, FDIM / 64, NEXP), 256, 0, stream>>>(W2, W2T, FDIM, HDIM);
    moe_gate_kernel<<<CAP, 64, 0, stream>>>(x, Wg, bg, wgt, src, ord);
    moe_dispatch_kernel<<<NEXP * CAP, 256, 0, stream>>>(x, wgt, src, buf);
    moe_gemm_kernel<HDIM, FDIM, true, 1><<<dim3(FDIM / 128, 4, NEXP), 256, 0, stream>>>(buf, W1T, b1, hmid);
    moe_gemm_kernel<FDIM, HDIM, false, 2><<<dim3(HDIM / 128, 4, NEXP * 2), 256, 0, stream>>>(hmid, W2T, b2, outb);
    moe_combine_kernel<<<8192, 256, 0, stream>>>(outb, ord, out);
}